// Round 3
// baseline (135.692 us; speedup 1.0000x reference)
//
#include <hip/hip_runtime.h>
#include <math.h>

// Shapes: B=32 T=64 N=16 A=20 D=128 S=32 E=64 H=256; batch=2048
// 3-launch pipeline:
//  k1: blocks 0..319   : X(2048x128) @ [W1a|Wfa|Wb|Wv1] -> h1(bf16), hf, b1buf, vrelu
//                        (register-prefetch pipelined fp32 tile GEMM)
//      blocks 320..639 : W1b -> Bp bf16 fragment-packed
//      blocks 640..2687: coalition masks -> coal(2048x16x20), arowbuf
//  k2: blocks 0..319  : w1 = |h1 @ W1b + b1b| MFMA bf16, reg-staged double-buffer,
//                        LDS-transposed coalesced epilogue
//      blocks 320..383: wf = |hf @ Wfb + bfb|  (64 blocks x 32 batches)
//  k3: per-batch, 256 threads (1 occupancy round): hidden/elu -> q_tot (2 barriers)
// out: q_tot (2048) ++ w_est (2048*16), fp32

#define BATCH 2048

typedef __attribute__((ext_vector_type(8))) short bf16x8;
typedef __attribute__((ext_vector_type(4))) float f32x4;

__device__ inline unsigned short f2bf(float f) {
    unsigned int u = __float_as_uint(f);
    unsigned int r = (u + 0x7FFFu + ((u >> 16) & 1u)) >> 16;
    return (unsigned short)r;
}
__device__ inline float bf2f(unsigned short s) {
    return __uint_as_float(((unsigned int)s) << 16);
}

// ---------------- k1: first-layer GEMM + Bp pack + coalition ----------------
__global__ __launch_bounds__(256) void k1(
    const float* __restrict__ X,
    const float* __restrict__ W1a, const float* __restrict__ b1a,
    const float* __restrict__ Wfa, const float* __restrict__ bfa,
    const float* __restrict__ Wb,  const float* __restrict__ bb,
    const float* __restrict__ Wv1, const float* __restrict__ bv1,
    const float* __restrict__ W1b,
    const float* __restrict__ actions, const int* __restrict__ gc,
    unsigned short* __restrict__ h1_bf, float* __restrict__ hf,
    float* __restrict__ b1buf, float* __restrict__ vrelu,
    unsigned short* __restrict__ Bp,
    float* __restrict__ coal, int* __restrict__ arowbuf)
{
    __shared__ __align__(16) char smem[8192];
    const int t = threadIdx.x, bid = blockIdx.x;

    if (bid >= 640) {
        // ---- coalition block: one batch b, 256 threads ----
        int b = bid - 640;
        int* q            = (int*)smem;                    // 32x16 ints, 2048B
        unsigned int* msk = (unsigned int*)(smem + 2048);  // 32x20 uints, 2560B
        int* aidx         = (int*)(smem + 2048 + 2560);    // 16 ints

        if (t < 128) ((uint4*)q)[t] = ((const uint4*)(gc + b * 512))[t];
        if (t < 160) ((uint4*)msk)[t] = make_uint4(0u, 0u, 0u, 0u);
        {
            float av = actions[b * 320 + t];
            if (av > 0.5f) aidx[t / 20] = t % 20;          // exactly one writer per agent
        }
        if (t < 64) {
            float av = actions[b * 320 + 256 + t];
            if (av > 0.5f) aidx[(256 + t) / 20] = (256 + t) % 20;
        }
        __syncthreads();
        if (t < 16) arowbuf[b * 16 + t] = 20 + aidx[t];
        {
            int s = t >> 4, j = t & 15;
            atomicOr(&msk[s * 20 + aidx[q[s * 16 + j]]], 1u << j);
            s += 16;
            atomicOr(&msk[s * 20 + aidx[q[s * 16 + j]]], 1u << j);
        }
        __syncthreads();
        for (int u = t; u < 320; u += 256) {
            int i = u / 20, a = u % 20;
            float acc = 0.f;
            #pragma unroll 8
            for (int s = 0; s < 32; ++s) {
                int g = q[s * 16 + i];
                acc += (float)(g * __popc(msk[s * 20 + a] & ((1u << g) - 1u)));
            }
            coal[(b * 16 + i) * 20 + a] = acc * (1.0f / 512.0f);
        }
        return;
    }

    if (bid >= 320) {
        // Bp[((nb*8+kc)*4+kg)*1024 + n_local*8 + j] = bf16(W1b[(kc*32+kg*8+j)*2560 + nb*128+n_local])
        int idx = (bid - 320) * 256 + t;  // 0..81919
        int n_local = idx & 127;
        int g = idx >> 7;
        int kg = g & 3, kcn = g >> 2;
        int kc = kcn & 7, nb = kcn >> 3;
        int kbase = kc * 32 + kg * 8;
        int col = nb * 128 + n_local;
        unsigned short o[8];
        #pragma unroll
        for (int j = 0; j < 8; ++j)
            o[j] = f2bf(W1b[(kbase + j) * 2560 + col]);
        *(uint4*)&Bp[idx * 8] = *(uint4*)o;
        return;
    }

    float (*As)[64] = (float(*)[64])smem;            // 16x64, 4096B
    float (*Bs)[64] = (float(*)[64])(smem + 4096);   // 16x64, 4096B

    const int nb = bid % 10, mb = bid / 10;
    const int m0 = mb * 64, n0 = nb * 64;
    const int tx = t & 15, ty = t >> 4;
    const int lm = t >> 2, lk = (t & 3) << 2;
    const int lkk = t >> 4, lnb = (t & 15) << 2;

    const float* Wsrc; const float* bsrc; int ldb, c0;
    if (nb < 4)       { Wsrc = W1a; bsrc = b1a; ldb = 256; c0 = n0; }
    else if (nb < 8)  { Wsrc = Wfa; bsrc = bfa; ldb = 256; c0 = n0 - 256; }
    else if (nb == 8) { Wsrc = Wb;  bsrc = bb;  ldb = 64;  c0 = 0; }
    else              { Wsrc = Wv1; bsrc = bv1; ldb = 64;  c0 = 0; }

    float c[4][4] = {{0}};
    // register-prefetch pipeline: load slab k0 while computing slab k0-16
    float4 av = *(const float4*)&X[(m0 + lm) * 128 + lk];
    float4 bv = *(const float4*)&Wsrc[lkk * ldb + c0 + lnb];
    for (int k0 = 0; k0 < 128; k0 += 16) {
        As[lk][lm] = av.x; As[lk+1][lm] = av.y; As[lk+2][lm] = av.z; As[lk+3][lm] = av.w;
        *(float4*)&Bs[lkk][lnb] = bv;
        __syncthreads();
        if (k0 < 112) {
            av = *(const float4*)&X[(m0 + lm) * 128 + k0 + 16 + lk];
            bv = *(const float4*)&Wsrc[(k0 + 16 + lkk) * ldb + c0 + lnb];
        }
        #pragma unroll
        for (int kk = 0; kk < 16; ++kk) {
            float4 a4 = *(const float4*)&As[kk][ty * 4];
            float4 b4 = *(const float4*)&Bs[kk][tx * 4];
            float aa[4] = {a4.x, a4.y, a4.z, a4.w};
            float bb4[4] = {b4.x, b4.y, b4.z, b4.w};
            #pragma unroll
            for (int i = 0; i < 4; ++i)
                #pragma unroll
                for (int j = 0; j < 4; ++j)
                    c[i][j] = fmaf(aa[i], bb4[j], c[i][j]);
        }
        __syncthreads();
    }
    const int ncol = c0 + tx * 4;
    float4 bias = *(const float4*)&bsrc[ncol];
    #pragma unroll
    for (int i = 0; i < 4; ++i) {
        int m = m0 + ty * 4 + i;
        float v0 = c[i][0] + bias.x, v1 = c[i][1] + bias.y;
        float v2 = c[i][2] + bias.z, v3 = c[i][3] + bias.w;
        if (nb < 4) {
            ushort4 o;
            o.x = f2bf(fmaxf(v0, 0.f)); o.y = f2bf(fmaxf(v1, 0.f));
            o.z = f2bf(fmaxf(v2, 0.f)); o.w = f2bf(fmaxf(v3, 0.f));
            *(ushort4*)&h1_bf[m * 256 + ncol] = o;
        } else if (nb < 8) {
            float4 o = { fmaxf(v0,0.f), fmaxf(v1,0.f), fmaxf(v2,0.f), fmaxf(v3,0.f) };
            *(float4*)&hf[m * 256 + ncol] = o;
        } else if (nb == 8) {
            float4 o = { v0, v1, v2, v3 };
            *(float4*)&b1buf[m * 64 + ncol] = o;
        } else {
            float4 o = { fmaxf(v0,0.f), fmaxf(v1,0.f), fmaxf(v2,0.f), fmaxf(v3,0.f) };
            *(float4*)&vrelu[m * 64 + ncol] = o;
        }
    }
}

// ---------------- k2: MFMA GEMM w1 (blocks 0..319, reg-staged dbuf) + wf (64 blocks) ----------------
#define AS_STRIDE 40
#define CS_STRIDE 136
__global__ __launch_bounds__(256) void k2(
    const unsigned short* __restrict__ A, const unsigned short* __restrict__ Bp,
    const float* __restrict__ bias, unsigned short* __restrict__ C,
    const float* __restrict__ hf, const float* __restrict__ Wfb,
    const float* __restrict__ bfb, float* __restrict__ wf)
{
    __shared__ __align__(16) char smem[36864];
    const int t = threadIdx.x, bid = blockIdx.x;

    if (bid < 320) {
        unsigned short* AsB[2] = { (unsigned short*)smem,
                                   (unsigned short*)(smem + 10240) };   // 128x40 bf16 each
        unsigned short* BsB[2] = { (unsigned short*)(smem + 20480),
                                   (unsigned short*)(smem + 28672) };   // 4096 bf16 each
        const int lane = t & 63, wave = t >> 6;
        const int ln15 = lane & 15, q4 = lane >> 4;
        const int nb = bid % 20, m0 = (bid / 20) * 128, n0 = nb * 128;
        const int wm = (wave & 1) * 64, wn = (wave >> 1) * 64;
        const int row0 = t >> 2, part0 = t & 3;   // row0 in 0..63; row0+64 for 2nd chunk

        f32x4 acc[4][4];
        #pragma unroll
        for (int i = 0; i < 4; ++i)
            #pragma unroll
            for (int j = 0; j < 4; ++j)
                acc[i][j] = (f32x4){0.f, 0.f, 0.f, 0.f};

        // prologue: stage kc=0 into buffer 0
        *(uint4*)&AsB[0][row0 * AS_STRIDE + part0 * 8] =
            *(const uint4*)&A[(m0 + row0) * 256 + part0 * 8];
        *(uint4*)&AsB[0][(row0 + 64) * AS_STRIDE + part0 * 8] =
            *(const uint4*)&A[(m0 + row0 + 64) * 256 + part0 * 8];
        {
            const uint4* src = (const uint4*)&Bp[(nb * 8) * 4096];
            ((uint4*)BsB[0])[t] = src[t];
            ((uint4*)BsB[0])[t + 256] = src[t + 256];
        }
        __syncthreads();

        for (int kc = 0; kc < 8; ++kc) {
            unsigned short* Ac = AsB[kc & 1];
            unsigned short* Bc = BsB[kc & 1];
            unsigned short* An = AsB[(kc & 1) ^ 1];
            unsigned short* Bn = BsB[(kc & 1) ^ 1];

            // issue next-tile global loads early (latency hides under MFMA)
            uint4 ra0, ra1, rb0, rb1;
            if (kc < 7) {
                ra0 = *(const uint4*)&A[(m0 + row0) * 256 + (kc + 1) * 32 + part0 * 8];
                ra1 = *(const uint4*)&A[(m0 + row0 + 64) * 256 + (kc + 1) * 32 + part0 * 8];
                const uint4* src = (const uint4*)&Bp[(nb * 8 + kc + 1) * 4096];
                rb0 = src[t];
                rb1 = src[t + 256];
            }

            bf16x8 af[4], bfr[4];
            #pragma unroll
            for (int mi = 0; mi < 4; ++mi)
                af[mi] = *(const bf16x8*)&Ac[(wm + mi * 16 + ln15) * AS_STRIDE + q4 * 8];
            #pragma unroll
            for (int ni = 0; ni < 4; ++ni)
                bfr[ni] = *(const bf16x8*)&Bc[(q4 * 128 + wn + ni * 16 + ln15) * 8];
            #pragma unroll
            for (int mi = 0; mi < 4; ++mi)
                #pragma unroll
                for (int ni = 0; ni < 4; ++ni)
                    acc[mi][ni] = __builtin_amdgcn_mfma_f32_16x16x32_bf16(af[mi], bfr[ni], acc[mi][ni], 0, 0, 0);

            if (kc < 7) {
                *(uint4*)&An[row0 * AS_STRIDE + part0 * 8] = ra0;
                *(uint4*)&An[(row0 + 64) * AS_STRIDE + part0 * 8] = ra1;
                ((uint4*)Bn)[t] = rb0;
                ((uint4*)Bn)[t + 256] = rb1;
            }
            __syncthreads();
        }

        // epilogue: bias+abs -> LDS tile (padded stride) -> coalesced uint4 stores
        unsigned short* Cs = (unsigned short*)smem;   // 128 x 136 bf16 = 34816B
        #pragma unroll
        for (int ni = 0; ni < 4; ++ni) {
            int coll = wn + ni * 16 + ln15;
            float bv = bias[n0 + coll];
            #pragma unroll
            for (int mi = 0; mi < 4; ++mi) {
                #pragma unroll
                for (int j = 0; j < 4; ++j) {
                    int rowl = wm + mi * 16 + q4 * 4 + j;
                    Cs[rowl * CS_STRIDE + coll] = f2bf(fabsf(acc[mi][ni][j] + bv));
                }
            }
        }
        __syncthreads();
        #pragma unroll
        for (int u = t; u < 2048; u += 256) {
            int row = u >> 4, c8 = (u & 15) << 3;
            *(uint4*)&C[(m0 + row) * 2560 + n0 + c8] =
                *(const uint4*)&Cs[row * CS_STRIDE + c8];
        }
    } else {
        // wf: 64 blocks x 32 batches; Wfb staged once per block per kc (4x less re-staging)
        float* hfs  = (float*)smem;            // [32][64], 8KB
        float* wfbs = (float*)(smem + 8192);   // [64][64], 16KB
        const int e = t & 63, mg = t >> 6;     // mg 0..3
        const int b0 = (bid - 320) * 32;
        float acc[8];
        #pragma unroll
        for (int r = 0; r < 8; ++r) acc[r] = 0.f;

        for (int kc = 0; kc < 4; ++kc) {
            for (int i = t; i < 1024; i += 256)
                ((float4*)wfbs)[i] = ((const float4*)(Wfb + kc * 64 * 64))[i];
            for (int i = t; i < 512; i += 256) {
                int r = i >> 4, p = i & 15;
                ((float4*)hfs)[i] = *(const float4*)&hf[(b0 + r) * 256 + kc * 64 + p * 4];
            }
            __syncthreads();
            #pragma unroll 8
            for (int k = 0; k < 64; ++k) {
                float wv = wfbs[k * 64 + e];
                #pragma unroll
                for (int r = 0; r < 8; ++r)
                    acc[r] = fmaf(hfs[(mg + r * 4) * 64 + k], wv, acc[r]);
            }
            __syncthreads();
        }
        float bf = bfb[e];
        #pragma unroll
        for (int r = 0; r < 8; ++r)
            wf[(b0 + mg + r * 4) * 64 + e] = fabsf(acc[r] + bf);
    }
}

// ---------------- k3: hidden/elu + q_tot, 256 threads (single occupancy round) ----------------
__global__ __launch_bounds__(256) void k3(
    const float* __restrict__ coal, const int* __restrict__ arowbuf,
    const unsigned short* __restrict__ w1, const float* __restrict__ b1buf,
    const float* __restrict__ wf, const float* __restrict__ vrelu,
    const float* __restrict__ Wv2, const float* __restrict__ bv2,
    const float* __restrict__ agent_qs, float* __restrict__ out)
{
    __shared__ __align__(16) unsigned short w1s[1280];   // w1 rows 0..19
    __shared__ __align__(16) float ins[16][20];
    __shared__ int arow[16];
    __shared__ float wq[16];
    const int t = threadIdx.x, b = blockIdx.x;

    // stage: 160 + 80 + 16 = 256 threads exactly, one barrier
    if (t < 160) {
        ((uint4*)w1s)[t] = ((const uint4*)(w1 + b * 2560))[t];
    } else if (t < 240) {
        ((uint4*)ins)[t - 160] = ((const uint4*)(coal + b * 320))[t - 160];
    } else {
        arow[t - 240] = arowbuf[b * 16 + (t - 240)];
    }
    __syncthreads();

    const int e = t & 63, wv = t >> 6;     // wv = 0..3
    const float b1v = b1buf[b * 64 + e];
    const float wfv = wf[b * 64 + e];
    const float vv  = vrelu[b * 64 + e] * Wv2[e];
    const float b2  = bv2[0];

    // issue the 4 gathered action-row loads up front
    float actv[4];
    #pragma unroll
    for (int pass = 0; pass < 4; ++pass)
        actv[pass] = bf2f(w1[b * 2560 + arow[pass * 4 + wv] * 64 + e]);

    #pragma unroll
    for (int pass = 0; pass < 4; ++pass) {
        const int i = pass * 4 + wv;
        float acc = b1v + actv[pass];
        #pragma unroll
        for (int k = 0; k < 20; ++k)
            acc = fmaf(ins[i][k], bf2f(w1s[k * 64 + e]), acc);
        float hidden = acc > 0.f ? acc : expm1f(acc);
        float p = hidden * wfv + vv;
        #pragma unroll
        for (int off = 32; off > 0; off >>= 1)
            p += __shfl_down(p, off, 64);
        if (e == 0) {
            float west = fabsf(p + b2);
            out[2048 + b * 16 + i] = west;
            wq[i] = west * agent_qs[b * 16 + i];
        }
    }
    __syncthreads();
    if (t < 16) {
        float v = wq[t];
        v += __shfl_down(v, 8, 64);
        v += __shfl_down(v, 4, 64);
        v += __shfl_down(v, 2, 64);
        v += __shfl_down(v, 1, 64);
        if (t == 0) out[b] = v;
    }
}

extern "C" void kernel_launch(void* const* d_in, const int* in_sizes, int n_in,
                              void* d_out, int out_size, void* d_ws, size_t ws_size,
                              hipStream_t stream) {
    const float* states   = (const float*)d_in[0];
    const float* actions  = (const float*)d_in[1];
    const float* agent_qs = (const float*)d_in[2];
    const int*   gc       = (const int*)d_in[4];
    const float* W1a = (const float*)d_in[5];
    const float* b1a = (const float*)d_in[6];
    const float* W1b = (const float*)d_in[7];
    const float* b1b = (const float*)d_in[8];
    const float* Wb  = (const float*)d_in[9];
    const float* bb  = (const float*)d_in[10];
    const float* Wfa = (const float*)d_in[11];
    const float* bfa = (const float*)d_in[12];
    const float* Wfb = (const float*)d_in[13];
    const float* bfb = (const float*)d_in[14];
    const float* Wv1 = (const float*)d_in[15];
    const float* bv1 = (const float*)d_in[16];
    const float* Wv2 = (const float*)d_in[17];
    const float* bv2 = (const float*)d_in[18];

    float* ws     = (float*)d_ws;
    float* hf     = ws;                      // 524288 f
    float* b1buf  = hf + 524288;             // 131072 f
    float* vrelu  = b1buf + 131072;          // 131072 f
    float* wfbuf  = vrelu + 131072;          // 131072 f
    unsigned short* h1_bf = (unsigned short*)(wfbuf + 131072); // 524288 us
    unsigned short* Bp    = h1_bf + 524288;                    // 655360 us
    unsigned short* w1    = Bp + 655360;                       // 5242880 us
    float* coal   = (float*)(w1 + 5242880);  // 655360 f
    int*   arowbuf = (int*)(coal + 655360);  // 32768 i
    float* out = (float*)d_out;

    k1<<<2688, 256, 0, stream>>>(states, W1a, b1a, Wfa, bfa, Wb, bb, Wv1, bv1,
                                 W1b, actions, gc, h1_bf, hf, b1buf, vrelu, Bp,
                                 coal, arowbuf);
    k2<<<384, 256, 0, stream>>>(h1_bf, Bp, b1b, w1, hf, Wfb, bfb, wfbuf);
    k3<<<BATCH, 256, 0, stream>>>(coal, arowbuf, w1, b1buf, wfbuf, vrelu,
                                  Wv2, bv2, agent_qs, out);
}

// Round 4
// 129.992 us; speedup vs baseline: 1.0438x; 1.0438x over previous
//
#include <hip/hip_runtime.h>
#include <math.h>

// Shapes: B=32 T=64 N=16 A=20 D=128 S=32 E=64 H=256; batch=2048
// 3-launch pipeline (best-verified configuration, R2 = 130.0 us):
//  k1: blocks 0..319   : X(2048x128) @ [W1a|Wfa|Wb|Wv1] -> h1(bf16), hf, b1buf, vrelu
//                        (register-prefetch pipelined fp32 tile GEMM)
//      blocks 320..639 : W1b -> Bp bf16 fragment-packed
//      blocks 640..2687: coalition masks -> coal(2048x16x20), arowbuf
//  k2: blocks 0..319  : w1 = |h1 @ W1b + b1b| MFMA bf16, reg-staged double-buffer,
//                        LDS-transposed coalesced epilogue
//      blocks 320..575: wf = |hf @ Wfb + bfb|  (256 blocks x 8 batches — short blocks
//                        that hide under the MFMA blocks; 64x32 variant regressed)
//  k3: per-batch, 512 threads: stage coal+w1rows -> hidden/elu -> q_tot (2 barriers;
//                        256-thread/4-pass variant regressed: longer serial chain)
// out: q_tot (2048) ++ w_est (2048*16), fp32

#define BATCH 2048

typedef __attribute__((ext_vector_type(8))) short bf16x8;
typedef __attribute__((ext_vector_type(4))) float f32x4;

__device__ inline unsigned short f2bf(float f) {
    unsigned int u = __float_as_uint(f);
    unsigned int r = (u + 0x7FFFu + ((u >> 16) & 1u)) >> 16;
    return (unsigned short)r;
}
__device__ inline float bf2f(unsigned short s) {
    return __uint_as_float(((unsigned int)s) << 16);
}

// ---------------- k1: first-layer GEMM + Bp pack + coalition ----------------
__global__ __launch_bounds__(256) void k1(
    const float* __restrict__ X,
    const float* __restrict__ W1a, const float* __restrict__ b1a,
    const float* __restrict__ Wfa, const float* __restrict__ bfa,
    const float* __restrict__ Wb,  const float* __restrict__ bb,
    const float* __restrict__ Wv1, const float* __restrict__ bv1,
    const float* __restrict__ W1b,
    const float* __restrict__ actions, const int* __restrict__ gc,
    unsigned short* __restrict__ h1_bf, float* __restrict__ hf,
    float* __restrict__ b1buf, float* __restrict__ vrelu,
    unsigned short* __restrict__ Bp,
    float* __restrict__ coal, int* __restrict__ arowbuf)
{
    __shared__ __align__(16) char smem[8192];
    const int t = threadIdx.x, bid = blockIdx.x;

    if (bid >= 640) {
        // ---- coalition block: one batch b, 256 threads ----
        int b = bid - 640;
        int* q            = (int*)smem;                    // 32x16 ints, 2048B
        unsigned int* msk = (unsigned int*)(smem + 2048);  // 32x20 uints, 2560B
        int* aidx         = (int*)(smem + 2048 + 2560);    // 16 ints

        if (t < 128) ((uint4*)q)[t] = ((const uint4*)(gc + b * 512))[t];
        if (t < 160) ((uint4*)msk)[t] = make_uint4(0u, 0u, 0u, 0u);
        {
            float av = actions[b * 320 + t];
            if (av > 0.5f) aidx[t / 20] = t % 20;          // exactly one writer per agent
        }
        if (t < 64) {
            float av = actions[b * 320 + 256 + t];
            if (av > 0.5f) aidx[(256 + t) / 20] = (256 + t) % 20;
        }
        __syncthreads();
        if (t < 16) arowbuf[b * 16 + t] = 20 + aidx[t];
        {
            int s = t >> 4, j = t & 15;
            atomicOr(&msk[s * 20 + aidx[q[s * 16 + j]]], 1u << j);
            s += 16;
            atomicOr(&msk[s * 20 + aidx[q[s * 16 + j]]], 1u << j);
        }
        __syncthreads();
        for (int u = t; u < 320; u += 256) {
            int i = u / 20, a = u % 20;
            float acc = 0.f;
            #pragma unroll 8
            for (int s = 0; s < 32; ++s) {
                int g = q[s * 16 + i];
                acc += (float)(g * __popc(msk[s * 20 + a] & ((1u << g) - 1u)));
            }
            coal[(b * 16 + i) * 20 + a] = acc * (1.0f / 512.0f);
        }
        return;
    }

    if (bid >= 320) {
        // Bp[((nb*8+kc)*4+kg)*1024 + n_local*8 + j] = bf16(W1b[(kc*32+kg*8+j)*2560 + nb*128+n_local])
        int idx = (bid - 320) * 256 + t;  // 0..81919
        int n_local = idx & 127;
        int g = idx >> 7;
        int kg = g & 3, kcn = g >> 2;
        int kc = kcn & 7, nb = kcn >> 3;
        int kbase = kc * 32 + kg * 8;
        int col = nb * 128 + n_local;
        unsigned short o[8];
        #pragma unroll
        for (int j = 0; j < 8; ++j)
            o[j] = f2bf(W1b[(kbase + j) * 2560 + col]);
        *(uint4*)&Bp[idx * 8] = *(uint4*)o;
        return;
    }

    float (*As)[64] = (float(*)[64])smem;            // 16x64, 4096B
    float (*Bs)[64] = (float(*)[64])(smem + 4096);   // 16x64, 4096B

    const int nb = bid % 10, mb = bid / 10;
    const int m0 = mb * 64, n0 = nb * 64;
    const int tx = t & 15, ty = t >> 4;
    const int lm = t >> 2, lk = (t & 3) << 2;
    const int lkk = t >> 4, lnb = (t & 15) << 2;

    const float* Wsrc; const float* bsrc; int ldb, c0;
    if (nb < 4)       { Wsrc = W1a; bsrc = b1a; ldb = 256; c0 = n0; }
    else if (nb < 8)  { Wsrc = Wfa; bsrc = bfa; ldb = 256; c0 = n0 - 256; }
    else if (nb == 8) { Wsrc = Wb;  bsrc = bb;  ldb = 64;  c0 = 0; }
    else              { Wsrc = Wv1; bsrc = bv1; ldb = 64;  c0 = 0; }

    float c[4][4] = {{0}};
    // register-prefetch pipeline: load slab k0 while computing slab k0-16
    float4 av = *(const float4*)&X[(m0 + lm) * 128 + lk];
    float4 bv = *(const float4*)&Wsrc[lkk * ldb + c0 + lnb];
    for (int k0 = 0; k0 < 128; k0 += 16) {
        As[lk][lm] = av.x; As[lk+1][lm] = av.y; As[lk+2][lm] = av.z; As[lk+3][lm] = av.w;
        *(float4*)&Bs[lkk][lnb] = bv;
        __syncthreads();
        if (k0 < 112) {
            av = *(const float4*)&X[(m0 + lm) * 128 + k0 + 16 + lk];
            bv = *(const float4*)&Wsrc[(k0 + 16 + lkk) * ldb + c0 + lnb];
        }
        #pragma unroll
        for (int kk = 0; kk < 16; ++kk) {
            float4 a4 = *(const float4*)&As[kk][ty * 4];
            float4 b4 = *(const float4*)&Bs[kk][tx * 4];
            float aa[4] = {a4.x, a4.y, a4.z, a4.w};
            float bb4[4] = {b4.x, b4.y, b4.z, b4.w};
            #pragma unroll
            for (int i = 0; i < 4; ++i)
                #pragma unroll
                for (int j = 0; j < 4; ++j)
                    c[i][j] = fmaf(aa[i], bb4[j], c[i][j]);
        }
        __syncthreads();
    }
    const int ncol = c0 + tx * 4;
    float4 bias = *(const float4*)&bsrc[ncol];
    #pragma unroll
    for (int i = 0; i < 4; ++i) {
        int m = m0 + ty * 4 + i;
        float v0 = c[i][0] + bias.x, v1 = c[i][1] + bias.y;
        float v2 = c[i][2] + bias.z, v3 = c[i][3] + bias.w;
        if (nb < 4) {
            ushort4 o;
            o.x = f2bf(fmaxf(v0, 0.f)); o.y = f2bf(fmaxf(v1, 0.f));
            o.z = f2bf(fmaxf(v2, 0.f)); o.w = f2bf(fmaxf(v3, 0.f));
            *(ushort4*)&h1_bf[m * 256 + ncol] = o;
        } else if (nb < 8) {
            float4 o = { fmaxf(v0,0.f), fmaxf(v1,0.f), fmaxf(v2,0.f), fmaxf(v3,0.f) };
            *(float4*)&hf[m * 256 + ncol] = o;
        } else if (nb == 8) {
            float4 o = { v0, v1, v2, v3 };
            *(float4*)&b1buf[m * 64 + ncol] = o;
        } else {
            float4 o = { fmaxf(v0,0.f), fmaxf(v1,0.f), fmaxf(v2,0.f), fmaxf(v3,0.f) };
            *(float4*)&vrelu[m * 64 + ncol] = o;
        }
    }
}

// ---------------- k2: MFMA GEMM w1 (blocks 0..319, reg-staged dbuf) + wf ----------------
#define AS_STRIDE 40
#define CS_STRIDE 136
__global__ __launch_bounds__(256) void k2(
    const unsigned short* __restrict__ A, const unsigned short* __restrict__ Bp,
    const float* __restrict__ bias, unsigned short* __restrict__ C,
    const float* __restrict__ hf, const float* __restrict__ Wfb,
    const float* __restrict__ bfb, float* __restrict__ wf)
{
    __shared__ __align__(16) char smem[36864];
    const int t = threadIdx.x, bid = blockIdx.x;

    if (bid < 320) {
        unsigned short* AsB[2] = { (unsigned short*)smem,
                                   (unsigned short*)(smem + 10240) };   // 128x40 bf16 each
        unsigned short* BsB[2] = { (unsigned short*)(smem + 20480),
                                   (unsigned short*)(smem + 28672) };   // 4096 bf16 each
        const int lane = t & 63, wave = t >> 6;
        const int ln15 = lane & 15, q4 = lane >> 4;
        const int nb = bid % 20, m0 = (bid / 20) * 128, n0 = nb * 128;
        const int wm = (wave & 1) * 64, wn = (wave >> 1) * 64;
        const int row0 = t >> 2, part0 = t & 3;   // row0 in 0..63; row0+64 for 2nd chunk

        f32x4 acc[4][4];
        #pragma unroll
        for (int i = 0; i < 4; ++i)
            #pragma unroll
            for (int j = 0; j < 4; ++j)
                acc[i][j] = (f32x4){0.f, 0.f, 0.f, 0.f};

        // prologue: stage kc=0 into buffer 0
        *(uint4*)&AsB[0][row0 * AS_STRIDE + part0 * 8] =
            *(const uint4*)&A[(m0 + row0) * 256 + part0 * 8];
        *(uint4*)&AsB[0][(row0 + 64) * AS_STRIDE + part0 * 8] =
            *(const uint4*)&A[(m0 + row0 + 64) * 256 + part0 * 8];
        {
            const uint4* src = (const uint4*)&Bp[(nb * 8) * 4096];
            ((uint4*)BsB[0])[t] = src[t];
            ((uint4*)BsB[0])[t + 256] = src[t + 256];
        }
        __syncthreads();

        for (int kc = 0; kc < 8; ++kc) {
            unsigned short* Ac = AsB[kc & 1];
            unsigned short* Bc = BsB[kc & 1];
            unsigned short* An = AsB[(kc & 1) ^ 1];
            unsigned short* Bn = BsB[(kc & 1) ^ 1];

            // issue next-tile global loads early (latency hides under MFMA)
            uint4 ra0, ra1, rb0, rb1;
            if (kc < 7) {
                ra0 = *(const uint4*)&A[(m0 + row0) * 256 + (kc + 1) * 32 + part0 * 8];
                ra1 = *(const uint4*)&A[(m0 + row0 + 64) * 256 + (kc + 1) * 32 + part0 * 8];
                const uint4* src = (const uint4*)&Bp[(nb * 8 + kc + 1) * 4096];
                rb0 = src[t];
                rb1 = src[t + 256];
            }

            bf16x8 af[4], bfr[4];
            #pragma unroll
            for (int mi = 0; mi < 4; ++mi)
                af[mi] = *(const bf16x8*)&Ac[(wm + mi * 16 + ln15) * AS_STRIDE + q4 * 8];
            #pragma unroll
            for (int ni = 0; ni < 4; ++ni)
                bfr[ni] = *(const bf16x8*)&Bc[(q4 * 128 + wn + ni * 16 + ln15) * 8];
            #pragma unroll
            for (int mi = 0; mi < 4; ++mi)
                #pragma unroll
                for (int ni = 0; ni < 4; ++ni)
                    acc[mi][ni] = __builtin_amdgcn_mfma_f32_16x16x32_bf16(af[mi], bfr[ni], acc[mi][ni], 0, 0, 0);

            if (kc < 7) {
                *(uint4*)&An[row0 * AS_STRIDE + part0 * 8] = ra0;
                *(uint4*)&An[(row0 + 64) * AS_STRIDE + part0 * 8] = ra1;
                ((uint4*)Bn)[t] = rb0;
                ((uint4*)Bn)[t + 256] = rb1;
            }
            __syncthreads();
        }

        // epilogue: bias+abs -> LDS tile (padded stride) -> coalesced uint4 stores
        unsigned short* Cs = (unsigned short*)smem;   // 128 x 136 bf16 = 34816B
        #pragma unroll
        for (int ni = 0; ni < 4; ++ni) {
            int coll = wn + ni * 16 + ln15;
            float bv = bias[n0 + coll];
            #pragma unroll
            for (int mi = 0; mi < 4; ++mi) {
                #pragma unroll
                for (int j = 0; j < 4; ++j) {
                    int rowl = wm + mi * 16 + q4 * 4 + j;
                    Cs[rowl * CS_STRIDE + coll] = f2bf(fabsf(acc[mi][ni][j] + bv));
                }
            }
        }
        __syncthreads();
        #pragma unroll
        for (int u = t; u < 2048; u += 256) {
            int row = u >> 4, c8 = (u & 15) << 3;
            *(uint4*)&C[(m0 + row) * 2560 + n0 + c8] =
                *(const uint4*)&Cs[row * CS_STRIDE + c8];
        }
    } else {
        float* hfs  = (float*)smem;            // [8][64], 2KB
        float* wfbs = (float*)(smem + 2048);   // [64][64], 16KB
        const int e = t & 63, mg = t >> 6;
        const int b0 = (bid - 320) * 8;
        float acc0 = 0.f, acc1 = 0.f;

        for (int kc = 0; kc < 4; ++kc) {
            for (int i = t; i < 1024; i += 256)
                ((float4*)wfbs)[i] = ((const float4*)(Wfb + kc * 64 * 64))[i];
            if (t < 128) {
                int r = t >> 4, p = t & 15;
                ((float4*)hfs)[t] = *(const float4*)&hf[(b0 + r) * 256 + kc * 64 + p * 4];
            }
            __syncthreads();
            #pragma unroll 8
            for (int k = 0; k < 64; ++k) {
                float wv = wfbs[k * 64 + e];
                acc0 = fmaf(hfs[mg * 64 + k], wv, acc0);
                acc1 = fmaf(hfs[(mg + 4) * 64 + k], wv, acc1);
            }
            __syncthreads();
        }
        float bf = bfb[e];
        wf[(b0 + mg) * 64 + e]     = fabsf(acc0 + bf);
        wf[(b0 + mg + 4) * 64 + e] = fabsf(acc1 + bf);
    }
}

// ---------------- k3: hidden/elu + q_tot only (coalition precomputed in k1) ----------------
__global__ __launch_bounds__(512) void k3(
    const float* __restrict__ coal, const int* __restrict__ arowbuf,
    const unsigned short* __restrict__ w1, const float* __restrict__ b1buf,
    const float* __restrict__ wf, const float* __restrict__ vrelu,
    const float* __restrict__ Wv2, const float* __restrict__ bv2,
    const float* __restrict__ agent_qs, float* __restrict__ out)
{
    __shared__ unsigned short w1s[1280];   // w1 rows 0..19
    __shared__ float ins[16][20];
    __shared__ int arow[16];
    __shared__ float wq[16];
    const int t = threadIdx.x, b = blockIdx.x;

    // stage (disjoint thread ranges, one barrier)
    if (t < 160) {
        ((uint4*)w1s)[t] = ((const uint4*)(w1 + b * 2560))[t];
    } else if (t < 480) {
        ((float*)ins)[t - 160] = coal[b * 320 + (t - 160)];
    } else if (t < 496) {
        arow[t - 480] = arowbuf[b * 16 + (t - 480)];
    }
    __syncthreads();

    const int e = t & 63, wv = t >> 6;     // wv = 0..7
    const float b1v = b1buf[b * 64 + e];
    const float wfv = wf[b * 64 + e];
    const float vv  = vrelu[b * 64 + e] * Wv2[e];
    const float b2  = bv2[0];

    #pragma unroll
    for (int pass = 0; pass < 2; ++pass) {
        const int i = wv + pass * 8;
        float acc = b1v;
        #pragma unroll
        for (int k = 0; k < 20; ++k)
            acc = fmaf(ins[i][k], bf2f(w1s[k * 64 + e]), acc);
        acc += bf2f(w1[b * 2560 + arow[i] * 64 + e]);   // one-hot action row
        float hidden = acc > 0.f ? acc : expm1f(acc);
        float p = hidden * wfv + vv;
        #pragma unroll
        for (int off = 32; off > 0; off >>= 1)
            p += __shfl_down(p, off, 64);
        if (e == 0) {
            float west = fabsf(p + b2);
            out[2048 + b * 16 + i] = west;
            wq[i] = west * agent_qs[b * 16 + i];
        }
    }
    __syncthreads();
    if (t < 16) {
        float v = wq[t];
        v += __shfl_down(v, 8, 64);
        v += __shfl_down(v, 4, 64);
        v += __shfl_down(v, 2, 64);
        v += __shfl_down(v, 1, 64);
        if (t == 0) out[b] = v;
    }
}

extern "C" void kernel_launch(void* const* d_in, const int* in_sizes, int n_in,
                              void* d_out, int out_size, void* d_ws, size_t ws_size,
                              hipStream_t stream) {
    const float* states   = (const float*)d_in[0];
    const float* actions  = (const float*)d_in[1];
    const float* agent_qs = (const float*)d_in[2];
    const int*   gc       = (const int*)d_in[4];
    const float* W1a = (const float*)d_in[5];
    const float* b1a = (const float*)d_in[6];
    const float* W1b = (const float*)d_in[7];
    const float* b1b = (const float*)d_in[8];
    const float* Wb  = (const float*)d_in[9];
    const float* bb  = (const float*)d_in[10];
    const float* Wfa = (const float*)d_in[11];
    const float* bfa = (const float*)d_in[12];
    const float* Wfb = (const float*)d_in[13];
    const float* bfb = (const float*)d_in[14];
    const float* Wv1 = (const float*)d_in[15];
    const float* bv1 = (const float*)d_in[16];
    const float* Wv2 = (const float*)d_in[17];
    const float* bv2 = (const float*)d_in[18];

    float* ws     = (float*)d_ws;
    float* hf     = ws;                      // 524288 f
    float* b1buf  = hf + 524288;             // 131072 f
    float* vrelu  = b1buf + 131072;          // 131072 f
    float* wfbuf  = vrelu + 131072;          // 131072 f
    unsigned short* h1_bf = (unsigned short*)(wfbuf + 131072); // 524288 us
    unsigned short* Bp    = h1_bf + 524288;                    // 655360 us
    unsigned short* w1    = Bp + 655360;                       // 5242880 us
    float* coal   = (float*)(w1 + 5242880);  // 655360 f
    int*   arowbuf = (int*)(coal + 655360);  // 32768 i
    float* out = (float*)d_out;

    k1<<<2688, 256, 0, stream>>>(states, W1a, b1a, Wfa, bfa, Wb, bb, Wv1, bv1,
                                 W1b, actions, gc, h1_bf, hf, b1buf, vrelu, Bp,
                                 coal, arowbuf);
    k2<<<576, 256, 0, stream>>>(h1_bf, Bp, b1b, w1, hf, Wfb, bfb, wfbuf);
    k3<<<BATCH, 512, 0, stream>>>(coal, arowbuf, w1, b1buf, wfbuf, vrelu,
                                  Wv2, bv2, agent_qs, out);
}